// Round 3
// baseline (67.138 us; speedup 1.0000x reference)
//
#include <hip/hip_runtime.h>
#include <math.h>

// Problem constants (from reference)
#define T_LEN   200
#define B_SZ    4096
#define V_SZ    100000
#define PAD_TOK 1

#define G        16             // columns per block
#define NBLOCKS  (B_SZ / G)     // 256
#define NTHREADS 512
#define HBITS    9
#define HSIZE    (1 << HBITS)   // 512-entry hash set per column, load 200/512
#define ROWS_PER_ITER (NTHREADS / G)                            // 32
#define MAX_K    ((T_LEN + ROWS_PER_ITER - 1) / ROWS_PER_ITER)  // 7

__global__ __launch_bounds__(NTHREADS) void bow_sigmoid_kernel(
    const int*   __restrict__ text,   // [T, B] int32 token ids
    const float* __restrict__ W,      // [1, V]
    const float* __restrict__ bias,   // [1]
    float*       __restrict__ out)    // [B, 1]
{
    __shared__ int   hset[G][HSIZE];
    __shared__ float acc[G];

    const int tid = threadIdx.x;
    const int blk = blockIdx.x;

    // XCD swizzle: blocks dispatch round-robin over 8 XCDs; make the column
    // ranges contiguous per XCD so text cache lines stay in one XCD's L2.
    const int g  = (blk & 7) * (NBLOCKS / 8) + (blk >> 3);
    const int b0 = g * G;

    // Clear hash sets (sentinel -1; token 0 is valid) and accumulators.
    for (int i = tid; i < G * HSIZE; i += NTHREADS) ((int*)hset)[i] = -1;
    if (tid < G) acc[tid] = 0.0f;
    __syncthreads();

    const int c  = tid & (G - 1);   // column within group
    const int t0 = tid >> 4;        // starting row, 0..31

    // Issue all token loads up front (independent, fully unrolled -> latency
    // overlap within the thread). Rows t0 + k*32; out-of-range -> PAD (skipped).
    int toks[MAX_K];
    #pragma unroll
    for (int k = 0; k < MAX_K; ++k) {
        const int t = t0 + k * ROWS_PER_ITER;
        toks[k] = (t < T_LEN) ? text[t * B_SZ + b0 + c] : PAD_TOK;
    }

    float sum = 0.0f;
    #pragma unroll
    for (int k = 0; k < MAX_K; ++k) {
        const int tok = toks[k];
        if (tok == PAD_TOK) continue;
        unsigned h = ((unsigned)tok * 2654435761u) >> (32 - HBITS);
        for (;;) {
            const int old = atomicCAS(&hset[c][h], -1, tok);
            if (old == -1) {        // first insert of this token in column c
                sum += W[tok];
                break;
            }
            if (old == tok) break;  // duplicate: set semantics, skip
            h = (h + 1) & (HSIZE - 1);
        }
    }

    // Reduce across the 4 lanes of each wave that share column c
    // (lanes c, c+16, c+32, c+48): butterfly over lane-id bits 4 and 5.
    sum += __shfl_xor(sum, 16, 64);
    sum += __shfl_xor(sum, 32, 64);
    if ((tid & 63) < G) atomicAdd(&acc[c], sum);   // one add per wave per column
    __syncthreads();

    if (tid < G) {
        const float s = acc[tid] + bias[0];
        out[b0 + tid] = 1.0f / (1.0f + expf(-s));
    }
}

extern "C" void kernel_launch(void* const* d_in, const int* in_sizes, int n_in,
                              void* d_out, int out_size, void* d_ws, size_t ws_size,
                              hipStream_t stream) {
    const int*   text = (const int*)d_in[0];    // [200, 4096] int32
    const float* W    = (const float*)d_in[1];  // [1, 100000]
    const float* bias = (const float*)d_in[2];  // [1]
    float*       out  = (float*)d_out;          // [4096, 1]

    bow_sigmoid_kernel<<<NBLOCKS, NTHREADS, 0, stream>>>(text, W, bias, out);
}

// Round 4
// 64.366 us; speedup vs baseline: 1.0431x; 1.0431x over previous
//
#include <hip/hip_runtime.h>
#include <math.h>

// Problem constants (from reference)
#define T_LEN   200
#define B_SZ    4096
#define V_SZ    100000
#define PAD_TOK 1

#define G        8              // columns per block
#define NBLOCKS  (B_SZ / G)     // 512  -> 4096 waves = 16 waves/CU
#define NTHREADS 512
#define HBITS    9
#define HSIZE    (1 << HBITS)   // 512-entry hash set per column, load 200/512
#define ROWS_PER_ITER (NTHREADS / G)                            // 64
#define MAX_K    ((T_LEN + ROWS_PER_ITER - 1) / ROWS_PER_ITER)  // 4

__global__ __launch_bounds__(NTHREADS) void bow_sigmoid_kernel(
    const int*   __restrict__ text,   // [T, B] int32 token ids
    const float* __restrict__ W,      // [1, V]
    const float* __restrict__ bias,   // [1]
    float*       __restrict__ out)    // [B, 1]
{
    __shared__ int   hset[G][HSIZE];  // 16 KB
    __shared__ float acc[G];

    const int tid = threadIdx.x;
    const int blk = blockIdx.x;

    // XCD swizzle: blocks dispatch round-robin over 8 XCDs; keep column
    // ranges contiguous per XCD so text cache lines stay in one XCD's L2.
    const int g  = (blk & 7) * (NBLOCKS / 8) + (blk >> 3);
    const int b0 = g * G;

    // Clear hash sets (sentinel -1; token 0 is valid) and accumulators.
    for (int i = tid; i < G * HSIZE; i += NTHREADS) ((int*)hset)[i] = -1;
    if (tid < G) acc[tid] = 0.0f;
    __syncthreads();

    const int c  = tid & (G - 1);   // column within group, 0..7
    const int t0 = tid >> 3;        // starting row, 0..63

    // Issue all token loads up front (independent, fully unrolled -> latency
    // overlap within the thread). Rows t0 + k*64; out-of-range -> PAD.
    int toks[MAX_K];
    #pragma unroll
    for (int k = 0; k < MAX_K; ++k) {
        const int t = t0 + k * ROWS_PER_ITER;
        toks[k] = (t < T_LEN) ? text[t * B_SZ + b0 + c] : PAD_TOK;
    }

    float sum = 0.0f;
    #pragma unroll
    for (int k = 0; k < MAX_K; ++k) {
        const int tok = toks[k];
        if (tok == PAD_TOK) continue;
        unsigned h = ((unsigned)tok * 2654435761u) >> (32 - HBITS);
        for (;;) {
            const int old = atomicCAS(&hset[c][h], -1, tok);
            if (old == -1) {        // first insert of this token in column c
                sum += W[tok];
                break;
            }
            if (old == tok) break;  // duplicate: set semantics, skip
            h = (h + 1) & (HSIZE - 1);
        }
    }

    // Reduce across the 8 lanes of each wave sharing column c
    // (lanes c, c+8, ..., c+56): butterfly over lane-id bits 3..5.
    sum += __shfl_xor(sum, 8, 64);
    sum += __shfl_xor(sum, 16, 64);
    sum += __shfl_xor(sum, 32, 64);
    if ((tid & 63) < G) atomicAdd(&acc[c], sum);   // one add per wave per column
    __syncthreads();

    if (tid < G) {
        const float s = acc[tid] + bias[0];
        out[b0 + tid] = 1.0f / (1.0f + expf(-s));
    }
}

extern "C" void kernel_launch(void* const* d_in, const int* in_sizes, int n_in,
                              void* d_out, int out_size, void* d_ws, size_t ws_size,
                              hipStream_t stream) {
    const int*   text = (const int*)d_in[0];    // [200, 4096] int32
    const float* W    = (const float*)d_in[1];  // [1, 100000]
    const float* bias = (const float*)d_in[2];  // [1]
    float*       out  = (float*)d_out;          // [4096, 1]

    bow_sigmoid_kernel<<<NBLOCKS, NTHREADS, 0, stream>>>(text, W, bias, out);
}